// Round 10
// baseline (488.395 us; speedup 1.0000x reference)
//
#include <hip/hip_runtime.h>
#include <cstdint>
#include <cstddef>

// Round 10: 4-wave (1 wave/SIMD) 256x256 GEMM, per-wave 128x128 output.
// 512-reg unified budget/wave (launch_bounds(256,1)): acc 256 AGPR +
// two operand sets (128 VGPR) -> true half-tile (kk) lookahead fits.
// Per K-tile: {h0: read kk1 || 64 MFMA(kk0); lgkm0+vm0; BAR}
//             {h1: stage t+2 || read kk0(t+1, buf q) || 64 MFMA(kk1)}
// One barrier/tile. LDS:MFMA work ratio 1536:2480 cyc (was 2300:2480).
// y = x_bf16 @ (w*bf16(scale))_bf16^T + bias  (x_dq == x exactly: pow2 scales)

typedef __attribute__((ext_vector_type(8))) __bf16 bf16x8;
typedef __attribute__((ext_vector_type(4))) float f32x4;

__device__ __forceinline__ unsigned short bf16rn(float f) {
  unsigned u = __builtin_bit_cast(unsigned, f);
  u = (u + 0x7FFFu + ((u >> 16) & 1u)) >> 16;
  return (unsigned short)u;
}
__device__ __forceinline__ float bf16tof(unsigned short h) {
  unsigned u = ((unsigned)h) << 16;
  return __builtin_bit_cast(float, u);
}
__device__ __forceinline__ void gload_lds16(const void* g, void* l) {
  __builtin_amdgcn_global_load_lds(
      (const __attribute__((address_space(1))) unsigned int*)g,
      (__attribute__((address_space(3))) unsigned int*)l, 16, 0, 0);
}

// ---------------- Phase A: fused prep (x->bf16, w*scale->bf16) -------------

__global__ __launch_bounds__(256) void k_prep(
    const float* __restrict__ x, const float* __restrict__ w,
    const float* __restrict__ sc, unsigned short* __restrict__ xb,
    unsigned short* __restrict__ wb, int K, int nblk, int blk,
    int n8x, int n8w) {
  int t = blockIdx.x * 256 + threadIdx.x;
  if (t < n8x) {
    const float4* p = (const float4*)x + (size_t)t * 2;
    float4 a = p[0], b = p[1];
    uint4 o;
    o.x = (unsigned)bf16rn(a.x) | ((unsigned)bf16rn(a.y) << 16);
    o.y = (unsigned)bf16rn(a.z) | ((unsigned)bf16rn(a.w) << 16);
    o.z = (unsigned)bf16rn(b.x) | ((unsigned)bf16rn(b.y) << 16);
    o.w = (unsigned)bf16rn(b.z) | ((unsigned)bf16rn(b.w) << 16);
    ((uint4*)xb)[t] = o;
  } else if (t - n8x < n8w) {
    int tw = t - n8x;
    size_t base = (size_t)tw * 8;
    int o_row = (int)(base / (size_t)K);
    int k = (int)(base % (size_t)K);
    float s = bf16tof(bf16rn(sc[(size_t)o_row * nblk + k / blk]));
    const float4* p = (const float4*)w + (size_t)tw * 2;
    float4 a = p[0], b = p[1];
    uint4 o;
    o.x = (unsigned)bf16rn(a.x * s) | ((unsigned)bf16rn(a.y * s) << 16);
    o.y = (unsigned)bf16rn(a.z * s) | ((unsigned)bf16rn(a.w * s) << 16);
    o.z = (unsigned)bf16rn(b.x * s) | ((unsigned)bf16rn(b.y * s) << 16);
    o.w = (unsigned)bf16rn(b.z * s) | ((unsigned)bf16rn(b.w * s) << 16);
    ((uint4*)wb)[tw] = o;
  }
}

// ---------------- Phase B: 4-wave 256^2 GEMM -------------------------------
// C[M][N] = A[M][K]*B[N][K]^T + bias. 256 thr = 4 waves (2Mx2N), per-wave
// 128x128 out = 8x8 frags of 16x16. LDS 128 KiB: 2 bufs x (A 32KB + B 32KB),
// XOR-swizzled byte ^= (row&7)<<4 (inverse-applied on global src, rule 21).

#define BM 256
#define BN 256
#define BK 64

#define BARF()                                  \
  do {                                          \
    __builtin_amdgcn_s_barrier();               \
    asm volatile("" ::: "memory");              \
    __builtin_amdgcn_sched_barrier(0);          \
  } while (0)
#define WAIT_VM0() asm volatile("s_waitcnt vmcnt(0)" ::: "memory")
#define WAIT_VM16() asm volatile("s_waitcnt vmcnt(16)" ::: "memory")
#define WAIT_LGKM0() asm volatile("s_waitcnt lgkmcnt(0)" ::: "memory")
#define SCHEDB() __builtin_amdgcn_sched_barrier(0)

// stage full K-tile tt (A 32KB + B 32KB, 16 gloads x 256 thr x 16B) into buf
#define STAGE16(bufp, tt)                                                  \
  do {                                                                     \
    _Pragma("unroll") for (int q_ = 0; q_ < 8; ++q_)                       \
        gload_lds16(Ag + (size_t)q_ * 32 * Ks + (size_t)(tt) * BK,         \
                    (bufp) + q_ * 4096 + tid16);                           \
    _Pragma("unroll") for (int q_ = 0; q_ < 8; ++q_)                       \
        gload_lds16(Bg + (size_t)q_ * 32 * Ks + (size_t)(tt) * BK,         \
                    (bufp) + 32768 + q_ * 4096 + tid16);                   \
  } while (0)

// read 8 A-frags (one kk): 8 x ds_read_b128 = 32 VGPR
#define READ_SA(dst, bufp, KO)                                             \
  _Pragma("unroll") for (int f_ = 0; f_ < 8; ++f_) {                       \
    dst[f_] = *(const bf16x8*)((bufp) + (wr * 128 + f_ * 16 + lr) * 128 +  \
                               (KO));                                      \
  }
// read 8 B-frags (one kk)
#define READ_SB(dst, bufp, KO)                                             \
  _Pragma("unroll") for (int g_ = 0; g_ < 8; ++g_) {                       \
    dst[g_] = *(const bf16x8*)((bufp) + 32768 +                            \
                               (wc * 128 + g_ * 16 + lr) * 128 + (KO));    \
  }
// 64 MFMA: full 8x8 frag grid, one kk
#define MFMA64(aset, bset)                                                 \
  _Pragma("unroll") for (int i_ = 0; i_ < 8; ++i_)                         \
  _Pragma("unroll") for (int j_ = 0; j_ < 8; ++j_)                         \
    acc[i_][j_] = __builtin_amdgcn_mfma_f32_16x16x32_bf16(                 \
        aset[i_], bset[j_], acc[i_][j_], 0, 0, 0);

__global__ __launch_bounds__(256, 1) void k_gemm4w(
    const unsigned short* __restrict__ A, const unsigned short* __restrict__ B,
    const float* __restrict__ bias, float* __restrict__ C,
    int M, int N, int K) {
  extern __shared__ __align__(16) char smem[];

  const int nbn = N / BN;
  const int nwg = gridDim.x;
  int bid = blockIdx.x;
  int wg = bid;
  if ((nwg & 7) == 0) wg = (bid & 7) * (nwg >> 3) + (bid >> 3);  // T1
  const int m0 = (wg / nbn) * BM;
  const int n0 = (wg % nbn) * BN;

  const int tid = threadIdx.x;
  const int lane = tid & 63;
  const int wid = tid >> 6;     // 4 waves
  const int wr = wid >> 1;      // 0..1 -> 128-row half
  const int wc = wid & 1;       // 0..1 -> 128-col half
  const int lr = lane & 15;
  const int ko0 = (((lane >> 4) * 16) ^ ((lane & 7) << 4));
  const int ko1 = ((64 | ((lane >> 4) * 16)) ^ ((lane & 7) << 4));
  const int tid16 = tid * 16;

  // staging: 256 thr, 16B each -> 32 rows per gload; pre-swizzled source
  const int srow = tid >> 3;                 // 0..31
  const int sgran = (tid & 7) ^ (srow & 7);  // inverse swizzle on source
  const size_t Ks = (size_t)K;
  const unsigned short* Ag = A + (size_t)(m0 + srow) * Ks + sgran * 8;
  const unsigned short* Bg = B + (size_t)(n0 + srow) * Ks + sgran * 8;

  f32x4 acc[8][8] = {};
  bf16x8 a0[8], a1[8], b0[8], b1[8];  // kk0 / kk1 operand sets

  const int NT = K / BK;  // >= 2 (launcher guards)

  // prologue: stage t0 -> buf0, t1 -> buf1; wait t0; read kk0(t0)
  STAGE16(smem, 0);
  STAGE16(smem + 65536, 1);
  WAIT_VM16();
  BARF();
  READ_SA(a0, smem, ko0);
  READ_SB(b0, smem, ko0);

  for (int t = 0; t < NT; ++t) {
    char* bp = smem + (size_t)(t & 1) * 65536;
    char* bq = smem + (size_t)((t & 1) ^ 1) * 65536;
    const bool hn1 = (t + 1) < NT;
    const bool hn2 = (t + 2) < NT;
    // h0: read kk1(t) from bp; 64 MFMA on kk0 set
    READ_SA(a1, bp, ko1);
    READ_SB(b1, bp, ko1);
    MFMA64(a0, b0);
    WAIT_LGKM0(); SCHEDB();   // own t-reads drained (WAR half)
    if (hn1) { WAIT_VM0(); }  // own t+1 stages drained (RAW half)
    BARF();                   // all waves: t-reads done, t+1 staged
    // h1: stage t+2 -> bp; read kk0(t+1) from bq; 64 MFMA on kk1 set
    if (hn2) { STAGE16(bp, t + 2); }
    if (hn1) { READ_SA(a0, bq, ko0); READ_SB(b0, bq, ko0); }
    MFMA64(a1, b1);
  }

  // epilogue: frag (i,j) at (i*16, j*16); col=lane&15, row=(lane>>4)*4+r
  const int col0 = n0 + wc * 128 + (lane & 15);
  const int row0 = m0 + wr * 128 + ((lane >> 4) << 2);
  float bj[8];
#pragma unroll
  for (int j = 0; j < 8; ++j) bj[j] = bias[col0 + j * 16];
#pragma unroll
  for (int i = 0; i < 8; ++i) {
#pragma unroll
    for (int r = 0; r < 4; ++r) {
      const size_t ro = (size_t)(row0 + i * 16 + r) * N;
#pragma unroll
      for (int j = 0; j < 8; ++j) {
        C[ro + col0 + j * 16] = acc[i][j][r] + bj[j];
      }
    }
  }
}

// ---------------- fallback (exact f32) ----------------

__global__ __launch_bounds__(256) void k_fallback(
    const float* __restrict__ x, const float* __restrict__ w,
    const float* __restrict__ sc, const float* __restrict__ bias,
    float* __restrict__ out, int T, int O, int K, int nblk, int blk) {
  long long idx = (long long)blockIdx.x * 256 + threadIdx.x;
  if (idx >= (long long)T * O) return;
  int row = (int)(idx / O), col = (int)(idx % O);
  const float* xr = x + (size_t)row * K;
  const float* wr = w + (size_t)col * K;
  const float* sr = sc + (size_t)col * nblk;
  float acc = 0.f;
  for (int b = 0; b < nblk; ++b) {
    float s = bf16tof(bf16rn(sr[b]));
    float part = 0.f;
    for (int k = 0; k < blk; k += 4) {
      float4 xa = *(const float4*)(xr + b * blk + k);
      float4 wa = *(const float4*)(wr + b * blk + k);
      part += xa.x * wa.x + xa.y * wa.y + xa.z * wa.z + xa.w * wa.w;
    }
    acc += part * s;
  }
  out[idx] = acc + bias[col];
}

extern "C" void kernel_launch(void* const* d_in, const int* in_sizes, int n_in,
                              void* d_out, int out_size, void* d_ws, size_t ws_size,
                              hipStream_t stream) {
  const float* x = (const float*)d_in[0];
  const float* w = (const float*)d_in[1];
  const float* sc = (const float*)d_in[2];
  const float* bias = (const float*)d_in[3];
  float* out = (float*)d_out;

  const int x_n = in_sizes[0];
  const int w_n = in_sizes[1];
  const int s_n = in_sizes[2];
  const int O = in_sizes[3];
  const int K = w_n / O;
  const int T = x_n / K;
  const int nblk = s_n / O;
  const int blk = K / nblk;

  const size_t need = (size_t)x_n * 2 + (size_t)w_n * 2;
  const bool tiled_ok = ws_size >= need && (K % (2 * BK)) == 0 &&
                        (T % BM) == 0 && (O % BN) == 0 && (blk % 8) == 0 &&
                        K >= 2 * BK;

  if (tiled_ok) {
    unsigned short* xb = (unsigned short*)d_ws;
    unsigned short* wb = xb + (size_t)x_n;
    int n8x = x_n / 8, n8w = w_n / 8;
    int nprep = n8x + n8w;
    k_prep<<<(nprep + 255) / 256, 256, 0, stream>>>(x, w, sc, xb, wb, K, nblk,
                                                    blk, n8x, n8w);
    hipFuncSetAttribute((const void*)k_gemm4w,
                        hipFuncAttributeMaxDynamicSharedMemorySize, 131072);
    dim3 grid((T / BM) * (O / BN));
    k_gemm4w<<<grid, 256, 131072, stream>>>(xb, wb, bias, out, T, O, K);
  } else {
    long long total = (long long)T * O;
    dim3 grid((unsigned)((total + 255) / 256));
    k_fallback<<<grid, 256, 0, stream>>>(x, w, sc, bias, out, T, O, K, nblk, blk);
  }
}